// Round 4
// baseline (857.343 us; speedup 1.0000x reference)
//
#include <hip/hip_runtime.h>
#include <cstdint>
#include <cstddef>

#define T_ 3
#define B_ 2
#define Y_ 192
#define X_ 192
#define YX_ 36864          // Y_*X_
#define N_ 221184          // T_*B_*Y_*X_
#define NS_ 73728          // B_*Y_*X_

typedef __attribute__((ext_vector_type(8))) short short8;
typedef __attribute__((ext_vector_type(4))) float f32x4;
typedef __attribute__((ext_vector_type(2))) float f32x2;
typedef unsigned short u16;
typedef unsigned int u32;

__device__ __forceinline__ u16 f2bf(float f){
  u32 x = __builtin_bit_cast(u32, f);
  x += 0x7fffu + ((x >> 16) & 1u);          // RNE
  return (u16)(x >> 16);
}
__device__ __forceinline__ float bflo(u32 u){ return __builtin_bit_cast(float, u << 16); }
__device__ __forceinline__ float bfhi(u32 u){ return __builtin_bit_cast(float, u & 0xffff0000u); }
__device__ __forceinline__ f32x2 bfp(u32 u){
  f32x2 r; r.x = bflo(u); r.y = bfhi(u); return r;
}
__device__ __forceinline__ int clampi(int v, int lo, int hi){ return v < lo ? lo : (v > hi ? hi : v); }
__device__ __forceinline__ f32x2 shfl2(f32x2 v, int m){
  f32x2 r; r.x = __shfl_xor(v.x, m); r.y = __shfl_xor(v.y, m); return r;
}

// ---------------- kernel 0: transpose weights to bf16, n-major ----------------
__global__ __launch_bounds__(256) void wt_kernel(
    const float* __restrict__ Wq, const float* __restrict__ Wk,
    const float* __restrict__ Wv, const float* __restrict__ Wo,
    u16* __restrict__ WT){
  int idx = blockIdx.x * 256 + threadIdx.x;     // 65536 total
  int g = idx >> 14;
  int r = (idx >> 7) & 127;                     // k
  int c = idx & 127;                            // n
  const float* W = (g == 0) ? Wq : (g == 1) ? Wk : (g == 2) ? Wv : Wo;
  WT[g * 16384 + c * 128 + r] = f2bf(W[r * 128 + c]);
}

// ---------------- kernel 1: fused QKV projection + embeddings (single pass) ----------------
// g-loop inside: 0=Q ((v+te+se)*0.25), 1=K (+te), 2=V. frames read once per block.
__global__ __launch_bounds__(256) void qkv_kernel(
    const float* __restrict__ frames, const u16* __restrict__ WT,
    u16* __restrict__ Qb, u16* __restrict__ Kb, u16* __restrict__ Vb,
    const float* __restrict__ temp_emb, const float* __restrict__ spatial_emb){
  __shared__ float tile[128 * 128];
  const int tid = threadIdx.x;
  const int w = tid >> 6, l = tid & 63;
  const int l16 = l & 15, lg = l >> 4;
  const int m0 = blockIdx.x * 128;

  for (int g = 0; g < 3; ++g){
    const u16* wt = WT + g * 16384;
    f32x4 acc[2][8];
    #pragma unroll
    for (int mr = 0; mr < 2; ++mr)
      #pragma unroll
      for (int nf = 0; nf < 8; ++nf)
        acc[mr][nf] = (f32x4){0.f, 0.f, 0.f, 0.f};

    #pragma unroll
    for (int ks = 0; ks < 4; ++ks){
      short8 af[2];
      #pragma unroll
      for (int mr = 0; mr < 2; ++mr){
        const float* ap = frames + (size_t)(m0 + w * 32 + mr * 16 + l16) * 128 + ks * 32 + lg * 8;
        const f32x4 a0 = *(const f32x4*)ap;
        const f32x4 a1 = *(const f32x4*)(ap + 4);
        short8 t;
        t[0] = (short)f2bf(a0[0]); t[1] = (short)f2bf(a0[1]);
        t[2] = (short)f2bf(a0[2]); t[3] = (short)f2bf(a0[3]);
        t[4] = (short)f2bf(a1[0]); t[5] = (short)f2bf(a1[1]);
        t[6] = (short)f2bf(a1[2]); t[7] = (short)f2bf(a1[3]);
        af[mr] = t;
      }
      #pragma unroll
      for (int nf = 0; nf < 8; ++nf){
        const short8 bf = *(const short8*)(wt + (nf * 16 + l16) * 128 + ks * 32 + lg * 8);
        acc[0][nf] = __builtin_amdgcn_mfma_f32_16x16x32_bf16(af[0], bf, acc[0][nf], 0, 0, 0);
        acc[1][nf] = __builtin_amdgcn_mfma_f32_16x16x32_bf16(af[1], bf, acc[1][nf], 0, 0, 0);
      }
    }

    if (g > 0) __syncthreads();                 // previous epilogue reads done
    #pragma unroll
    for (int mr = 0; mr < 2; ++mr)
      #pragma unroll
      for (int nf = 0; nf < 8; ++nf)
        #pragma unroll
        for (int i = 0; i < 4; ++i)
          tile[(w * 32 + mr * 16 + lg * 4 + i) * 128 + nf * 16 + l16] = acc[mr][nf][i];
    __syncthreads();

    u16* outp = (g == 0) ? Qb : (g == 1) ? Kb : Vb;
    #pragma unroll
    for (int it = 0; it < 16; ++it){
      const int idx = it * 256 + tid;
      const int r = idx >> 5;
      const int c4 = (idx & 31) * 4;
      f32x4 v = *(const f32x4*)&tile[r * 128 + c4];
      const int p = m0 + r;
      const int t = p / (B_ * YX_);
      if (g <= 1){                          // temporal emb for Q and K
        const float* te = temp_emb + t * 128 + c4;
        v[0] += te[0]; v[1] += te[1]; v[2] += te[2]; v[3] += te[3];
      }
      if (g == 0){                          // query spatial emb + 1/sqrt(F) prescale
        const int yx = p % YX_;
        const int y = yx / X_, x = yx % X_;
        const int yrel = y - clampi(y, 2, Y_ - 3) + 2;
        const int xrel = x - clampi(x, 2, X_ - 3) + 2;
        const float* se = spatial_emb + (yrel * 5 + xrel) * 128 + c4;
        v[0] = (v[0] + se[0]) * 0.25f; v[1] = (v[1] + se[1]) * 0.25f;
        v[2] = (v[2] + se[2]) * 0.25f; v[3] = (v[3] + se[3]) * 0.25f;
      }
      uint2 pk;
      pk.x = (u32)f2bf(v[0]) | ((u32)f2bf(v[1]) << 16);
      pk.y = (u32)f2bf(v[2]) | ((u32)f2bf(v[3]) << 16);
      *(uint2*)(outp + (size_t)p * 128 + c4) = pk;
    }
  }
}

// ---------------- kernel 2: scalar attention, 4 key-slots x (8 heads x 2 halves) ----------------
// 1 wave per site; lane (slot=l>>4, hh=l&15) owns 8 ch (= half of head hh>>1) for keys slot, slot+4, ...
__global__ __launch_bounds__(256) void attn_kernel(
    const u16* __restrict__ Kb, const u16* __restrict__ Vb,
    u16* __restrict__ Qb, const float* __restrict__ se){
  __shared__ float qse[4][3][25][8];
  const int tid = threadIdx.x;
  const int w = tid >> 6, l = tid & 63;
  const int slot = l >> 4, hh = l & 15;
  const int h = hh >> 1;
  const int site = blockIdx.x * 4 + w;
  const int b = site / YX_;
  const int yx = site % YX_;
  const int y = yx / X_, x = yx % X_;
  const int yc = clampi(y, 2, Y_ - 3), xc = clampi(x, 2, X_ - 3);

  // Q load + unpack (already prescaled, + temp & query-spatial emb): 8 ch per lane
  f32x2 qpf[3][4];
  #pragma unroll
  for (int q = 0; q < 3; ++q){
    const u16* qp = Qb + ((size_t)((q * B_ + b) * Y_ + y) * X_ + x) * 128 + hh * 8;
    const uint4 a = *(const uint4*)qp;
    qpf[q][0] = bfp(a.x); qpf[q][1] = bfp(a.y); qpf[q][2] = bfp(a.z); qpf[q][3] = bfp(a.w);
  }

  // qse[q][s][h] = Qs . spatial_emb[s] (per head), s striped over slots
  #pragma unroll
  for (int sj = 0; sj < 7; ++sj){
    const int so = sj * 4 + slot;
    if (so < 25){
      const float* sp = se + so * 128 + hh * 8;
      const f32x4 s0 = *(const f32x4*)sp;
      const f32x4 s1 = *(const f32x4*)(sp + 4);
      f32x2 sf[4];
      sf[0] = (f32x2){s0[0], s0[1]}; sf[1] = (f32x2){s0[2], s0[3]};
      sf[2] = (f32x2){s1[0], s1[1]}; sf[3] = (f32x2){s1[2], s1[3]};
      #pragma unroll
      for (int q = 0; q < 3; ++q){
        f32x2 dv = qpf[q][0] * sf[0];
        dv += qpf[q][1] * sf[1];
        dv += qpf[q][2] * sf[2];
        dv += qpf[q][3] * sf[3];
        float d = dv.x + dv.y;
        d += __shfl_xor(d, 1);
        if (!(l & 1)) qse[w][q][so][h] = d;
      }
    }
  }
  __syncthreads();

  float ll[3] = {0.f, 0.f, 0.f};
  f32x2 acc[3][4];
  #pragma unroll
  for (int q = 0; q < 3; ++q)
    #pragma unroll
    for (int i = 0; i < 4; ++i) acc[q][i] = (f32x2){0.f, 0.f};

  #pragma unroll 2
  for (int j = 0; j < 19; ++j){
    const int kk = j * 4 + slot;
    const bool valid = (kk < 75);
    const int kkc = valid ? kk : 74;
    const int t = (kkc >= 50) ? 2 : ((kkc >= 25) ? 1 : 0);
    const int s = kkc - t * 25;
    const int dy = s / 5, dx = s - dy * 5;
    const int ky = yc + dy - 2, kx = xc + dx - 2;
    const size_t roff = ((size_t)(((t * B_ + b) * Y_ + ky) * X_ + kx)) * 128 + hh * 8;
    const uint4 ku = *(const uint4*)(Kb + roff);
    const uint4 vu = *(const uint4*)(Vb + roff);
    f32x2 kf[4], vf[4];
    kf[0] = bfp(ku.x); kf[1] = bfp(ku.y); kf[2] = bfp(ku.z); kf[3] = bfp(ku.w);
    vf[0] = bfp(vu.x); vf[1] = bfp(vu.y); vf[2] = bfp(vu.z); vf[3] = bfp(vu.w);

    #pragma unroll
    for (int q = 0; q < 3; ++q){
      f32x2 dv = qpf[q][0] * kf[0];
      dv += qpf[q][1] * kf[1];
      dv += qpf[q][2] * kf[2];
      dv += qpf[q][3] * kf[3];
      float d = dv.x + dv.y;
      d += __shfl_xor(d, 1);
      d += qse[w][q][s][h];
      const float p = valid ? __expf(d) : 0.f;
      ll[q] += p;
      const f32x2 pp = {p, p};
      acc[q][0] += pp * vf[0];
      acc[q][1] += pp * vf[1];
      acc[q][2] += pp * vf[2];
      acc[q][3] += pp * vf[3];
    }
  }

  // merge across the 4 key-slot groups (lanes xor 16/32 share the same hh)
  #pragma unroll
  for (int q = 0; q < 3; ++q){
    ll[q] += __shfl_xor(ll[q], 16);
    ll[q] += __shfl_xor(ll[q], 32);
    #pragma unroll
    for (int i = 0; i < 4; ++i){
      acc[q][i] += shfl2(acc[q][i], 16);
      acc[q][i] += shfl2(acc[q][i], 32);
    }
  }

  // slot-group q (<3) stores query-frame q's output over its Q row (16 lanes x 16B = 256B)
  #pragma unroll
  for (int q = 0; q < 3; ++q){
    if (slot == q){
      const float inv = 1.0f / ll[q];
      uint4 o;
      f32x2 t0 = acc[q][0] * inv, t1 = acc[q][1] * inv;
      f32x2 t2 = acc[q][2] * inv, t3 = acc[q][3] * inv;
      o.x = (u32)f2bf(t0.x) | ((u32)f2bf(t0.y) << 16);
      o.y = (u32)f2bf(t1.x) | ((u32)f2bf(t1.y) << 16);
      o.z = (u32)f2bf(t2.x) | ((u32)f2bf(t2.y) << 16);
      o.w = (u32)f2bf(t3.x) | ((u32)f2bf(t3.y) << 16);
      u16* dst = Qb + ((size_t)((q * B_ + b) * Y_ + y) * X_ + x) * 128 + hh * 8;
      *(uint4*)dst = o;
    }
  }
}

// ---------------- kernel 3: output projection (attnout x Wout) ----------------
__global__ __launch_bounds__(256) void out_kernel(
    const u16* __restrict__ Ab, const u16* __restrict__ WT3, float* __restrict__ out){
  const int tid = threadIdx.x;
  const int w = tid >> 6, l = tid & 63;
  const int l16 = l & 15, lg = l >> 4;
  const int m0 = blockIdx.x * 128;

  f32x4 acc[2][8];
  #pragma unroll
  for (int mr = 0; mr < 2; ++mr)
    #pragma unroll
    for (int nf = 0; nf < 8; ++nf)
      acc[mr][nf] = (f32x4){0.f, 0.f, 0.f, 0.f};

  #pragma unroll
  for (int ks = 0; ks < 4; ++ks){
    short8 af[2];
    #pragma unroll
    for (int mr = 0; mr < 2; ++mr)
      af[mr] = *(const short8*)(Ab + (size_t)(m0 + w * 32 + mr * 16 + l16) * 128 + ks * 32 + lg * 8);
    #pragma unroll
    for (int nf = 0; nf < 8; ++nf){
      const short8 bf = *(const short8*)(WT3 + (nf * 16 + l16) * 128 + ks * 32 + lg * 8);
      acc[0][nf] = __builtin_amdgcn_mfma_f32_16x16x32_bf16(af[0], bf, acc[0][nf], 0, 0, 0);
      acc[1][nf] = __builtin_amdgcn_mfma_f32_16x16x32_bf16(af[1], bf, acc[1][nf], 0, 0, 0);
    }
  }

  #pragma unroll
  for (int mr = 0; mr < 2; ++mr)
    #pragma unroll
    for (int nf = 0; nf < 8; ++nf)
      #pragma unroll
      for (int i = 0; i < 4; ++i)
        out[(size_t)(m0 + w * 32 + mr * 16 + lg * 4 + i) * 128 + nf * 16 + l16] = acc[mr][nf][i];
}

extern "C" void kernel_launch(void* const* d_in, const int* in_sizes, int n_in,
                              void* d_out, int out_size, void* d_ws, size_t ws_size,
                              hipStream_t stream){
  const float* frames      = (const float*)d_in[0];
  const float* Wq          = (const float*)d_in[1];
  const float* Wk          = (const float*)d_in[2];
  const float* Wv          = (const float*)d_in[3];
  const float* Wo          = (const float*)d_in[4];
  const float* temp_emb    = (const float*)d_in[5];
  const float* spatial_emb = (const float*)d_in[6];

  u16* WT = (u16*)d_ws;                        // [4][128][128] bf16 (n-major)
  u16* Qb = WT + 4 * 16384;                    // [N_][128] bf16 (Q, then attnout)
  u16* Kb = (u16*)d_out;                       // [N_][128] bf16 — reuse output buffer
  u16* Vb = Kb + (size_t)N_ * 128;             // [N_][128] bf16 — exactly fills d_out
  float* out = (float*)d_out;

  wt_kernel<<<256, 256, 0, stream>>>(Wq, Wk, Wv, Wo, WT);
  qkv_kernel<<<N_ / 128, 256, 0, stream>>>(frames, WT, Qb, Kb, Vb, temp_emb, spatial_emb);
  attn_kernel<<<NS_ / 4, 256, 0, stream>>>(Kb, Vb, Qb, spatial_emb);
  out_kernel<<<N_ / 128, 256, 0, stream>>>(Qb, WT + 3 * 16384, out);
}

// Round 5
// 497.644 us; speedup vs baseline: 1.7228x; 1.7228x over previous
//
#include <hip/hip_runtime.h>
#include <cstdint>
#include <cstddef>

#define T_ 3
#define B_ 2
#define Y_ 192
#define X_ 192
#define YX_ 36864          // Y_*X_
#define N_ 221184          // T_*B_*Y_*X_
#define NS_ 73728          // B_*Y_*X_

typedef __attribute__((ext_vector_type(8))) short short8;
typedef __attribute__((ext_vector_type(4))) float f32x4;
typedef __attribute__((ext_vector_type(2))) float f32x2;
typedef unsigned short u16;
typedef unsigned int u32;

__device__ __forceinline__ u16 f2bf(float f){
  u32 x = __builtin_bit_cast(u32, f);
  x += 0x7fffu + ((x >> 16) & 1u);          // RNE
  return (u16)(x >> 16);
}
__device__ __forceinline__ float bflo(u32 u){ return __builtin_bit_cast(float, u << 16); }
__device__ __forceinline__ float bfhi(u32 u){ return __builtin_bit_cast(float, u & 0xffff0000u); }
__device__ __forceinline__ f32x2 bfp(u32 u){
  f32x2 r; r.x = bflo(u); r.y = bfhi(u); return r;
}
__device__ __forceinline__ int clampi(int v, int lo, int hi){ return v < lo ? lo : (v > hi ? hi : v); }
__device__ __forceinline__ f32x2 shfl2(f32x2 v, int m){
  f32x2 r; r.x = __shfl_xor(v.x, m); r.y = __shfl_xor(v.y, m); return r;
}

#if __has_builtin(__builtin_amdgcn_fdot2_f32_bf16)
typedef __attribute__((ext_vector_type(2))) __bf16 bf16x2;
__device__ __forceinline__ float dot2bf(u32 a, u32 b, float c){
  return __builtin_amdgcn_fdot2_f32_bf16(__builtin_bit_cast(bf16x2, a),
                                         __builtin_bit_cast(bf16x2, b), c, false);
}
#else
__device__ __forceinline__ float dot2bf(u32 a, u32 b, float c){
  return fmaf(bfhi(a), bfhi(b), fmaf(bflo(a), bflo(b), c));
}
#endif

// ---------------- kernel 0: weights -> bf16 n-major; spatial_emb -> bf16 ----------------
__global__ __launch_bounds__(256) void wt_kernel(
    const float* __restrict__ Wq, const float* __restrict__ Wk,
    const float* __restrict__ Wv, const float* __restrict__ Wo,
    const float* __restrict__ spatial_emb, u16* __restrict__ WT, u16* __restrict__ se_bf){
  int idx = blockIdx.x * 256 + threadIdx.x;
  if (idx < 65536){
    int g = idx >> 14;
    int r = (idx >> 7) & 127;                   // k
    int c = idx & 127;                          // n
    const float* W = (g == 0) ? Wq : (g == 1) ? Wk : (g == 2) ? Wv : Wo;
    WT[g * 16384 + c * 128 + r] = f2bf(W[r * 128 + c]);
  } else if (idx < 65536 + 3200){
    se_bf[idx - 65536] = f2bf(spatial_emb[idx - 65536]);
  }
}

// ---------------- kernel 1: fused QKV projection + embeddings ----------------
// grid (N_/128, 3); g 0=Q ((v+te+se)*0.25), 1=K (+te), 2=V
__global__ __launch_bounds__(256) void qkv_kernel(
    const float* __restrict__ frames, const u16* __restrict__ WT,
    u16* __restrict__ Qb, u16* __restrict__ Kb, u16* __restrict__ Vb,
    const float* __restrict__ temp_emb, const float* __restrict__ spatial_emb){
  __shared__ float tile[128 * 128];
  const int tid = threadIdx.x;
  const int w = tid >> 6, l = tid & 63;
  const int l16 = l & 15, lg = l >> 4;
  const int g = blockIdx.y;
  const int m0 = blockIdx.x * 128;
  const u16* wt = WT + g * 16384;

  f32x4 acc[2][8];
  #pragma unroll
  for (int mr = 0; mr < 2; ++mr)
    #pragma unroll
    for (int nf = 0; nf < 8; ++nf)
      acc[mr][nf] = (f32x4){0.f, 0.f, 0.f, 0.f};

  #pragma unroll
  for (int ks = 0; ks < 4; ++ks){
    short8 af[2];
    #pragma unroll
    for (int mr = 0; mr < 2; ++mr){
      const float* ap = frames + (size_t)(m0 + w * 32 + mr * 16 + l16) * 128 + ks * 32 + lg * 8;
      const f32x4 a0 = *(const f32x4*)ap;
      const f32x4 a1 = *(const f32x4*)(ap + 4);
      short8 t;
      t[0] = (short)f2bf(a0[0]); t[1] = (short)f2bf(a0[1]);
      t[2] = (short)f2bf(a0[2]); t[3] = (short)f2bf(a0[3]);
      t[4] = (short)f2bf(a1[0]); t[5] = (short)f2bf(a1[1]);
      t[6] = (short)f2bf(a1[2]); t[7] = (short)f2bf(a1[3]);
      af[mr] = t;
    }
    #pragma unroll
    for (int nf = 0; nf < 8; ++nf){
      const short8 bf = *(const short8*)(wt + (nf * 16 + l16) * 128 + ks * 32 + lg * 8);
      acc[0][nf] = __builtin_amdgcn_mfma_f32_16x16x32_bf16(af[0], bf, acc[0][nf], 0, 0, 0);
      acc[1][nf] = __builtin_amdgcn_mfma_f32_16x16x32_bf16(af[1], bf, acc[1][nf], 0, 0, 0);
    }
  }

  #pragma unroll
  for (int mr = 0; mr < 2; ++mr)
    #pragma unroll
    for (int nf = 0; nf < 8; ++nf)
      #pragma unroll
      for (int i = 0; i < 4; ++i)
        tile[(w * 32 + mr * 16 + lg * 4 + i) * 128 + nf * 16 + l16] = acc[mr][nf][i];
  __syncthreads();

  u16* outp = (g == 0) ? Qb : (g == 1) ? Kb : Vb;
  #pragma unroll
  for (int it = 0; it < 16; ++it){
    const int idx = it * 256 + tid;
    const int r = idx >> 5;
    const int c4 = (idx & 31) * 4;
    f32x4 v = *(const f32x4*)&tile[r * 128 + c4];
    const int p = m0 + r;
    const int t = p / (B_ * YX_);
    if (g <= 1){                          // temporal emb for Q and K
      const float* te = temp_emb + t * 128 + c4;
      v[0] += te[0]; v[1] += te[1]; v[2] += te[2]; v[3] += te[3];
    }
    if (g == 0){                          // query spatial emb + 1/sqrt(F) prescale
      const int yx = p % YX_;
      const int y = yx / X_, x = yx % X_;
      const int yrel = y - clampi(y, 2, Y_ - 3) + 2;
      const int xrel = x - clampi(x, 2, X_ - 3) + 2;
      const float* se = spatial_emb + (yrel * 5 + xrel) * 128 + c4;
      v[0] = (v[0] + se[0]) * 0.25f; v[1] = (v[1] + se[1]) * 0.25f;
      v[2] = (v[2] + se[2]) * 0.25f; v[3] = (v[3] + se[3]) * 0.25f;
    }
    uint2 pk;
    pk.x = (u32)f2bf(v[0]) | ((u32)f2bf(v[1]) << 16);
    pk.y = (u32)f2bf(v[2]) | ((u32)f2bf(v[3]) << 16);
    *(uint2*)(outp + (size_t)p * 128 + c4) = pk;
  }
}

// ---------------- kernel 2: scalar attention, 8 key-slots x 8 heads ----------------
// 1 wave per site; lane (slot=l>>3, h=l&7) owns all 16 ch of head h for keys slot, slot+8, ...
// Q/K stay bf16-packed; score via v_dot2_f32_bf16 — no shuffle, no K unpack.
__global__ __launch_bounds__(256, 4) void attn_kernel(
    const u16* __restrict__ Kb, const u16* __restrict__ Vb,
    u16* __restrict__ Qb, const u16* __restrict__ se_bf){
  __shared__ float qse[4][3][25][8];
  const int tid = threadIdx.x;
  const int w = tid >> 6, l = tid & 63;
  const int slot = l >> 3, h = l & 7;
  const int site = blockIdx.x * 4 + w;
  const int b = site / YX_;
  const int yx = site % YX_;
  const int y = yx / X_, x = yx % X_;
  const int yc = clampi(y, 2, Y_ - 3), xc = clampi(x, 2, X_ - 3);

  // Q packed (already prescaled by 0.25, + temp & query-spatial emb)
  u32 qp[3][8];
  #pragma unroll
  for (int q = 0; q < 3; ++q){
    const u16* qptr = Qb + ((size_t)((q * B_ + b) * Y_ + y) * X_ + x) * 128 + h * 16;
    const uint4 a = *(const uint4*)qptr;
    const uint4 c = *(const uint4*)(qptr + 8);
    qp[q][0] = a.x; qp[q][1] = a.y; qp[q][2] = a.z; qp[q][3] = a.w;
    qp[q][4] = c.x; qp[q][5] = c.y; qp[q][6] = c.z; qp[q][7] = c.w;
  }

  // qse[q][so][h] = Qs . spatial_emb[so] (per head), so striped over slots
  #pragma unroll
  for (int sj = 0; sj < 4; ++sj){
    const int so = sj * 8 + slot;
    if (so < 25){
      const u16* sp = se_bf + so * 128 + h * 16;
      const uint4 e0 = *(const uint4*)sp;
      const uint4 e1 = *(const uint4*)(sp + 8);
      u32 ep[8] = {e0.x, e0.y, e0.z, e0.w, e1.x, e1.y, e1.z, e1.w};
      #pragma unroll
      for (int q = 0; q < 3; ++q){
        float d = 0.f;
        #pragma unroll
        for (int i = 0; i < 8; ++i) d = dot2bf(qp[q][i], ep[i], d);
        qse[w][q][so][h] = d;
      }
    }
  }
  __syncthreads();

  float ll[3] = {0.f, 0.f, 0.f};
  f32x2 acc[3][8];
  #pragma unroll
  for (int q = 0; q < 3; ++q)
    #pragma unroll
    for (int i = 0; i < 8; ++i) acc[q][i] = (f32x2){0.f, 0.f};

  #pragma unroll
  for (int j = 0; j < 10; ++j){
    const int kk = j * 8 + slot;
    const bool valid = (j < 9) || (slot < 3);    // j is compile-time: folds for j<9
    const int kkc = valid ? kk : 74;
    const int t = (kkc >= 50) ? 2 : ((kkc >= 25) ? 1 : 0);
    const int s = kkc - t * 25;
    const int dy = s / 5, dx = s - dy * 5;
    const int ky = yc + dy - 2, kx = xc + dx - 2;
    const size_t roff = ((size_t)(((t * B_ + b) * Y_ + ky) * X_ + kx)) * 128 + h * 16;
    const uint4 k0 = *(const uint4*)(Kb + roff);
    const uint4 k1 = *(const uint4*)(Kb + roff + 8);
    const uint4 v0 = *(const uint4*)(Vb + roff);
    const uint4 v1 = *(const uint4*)(Vb + roff + 8);
    const u32 kp[8] = {k0.x, k0.y, k0.z, k0.w, k1.x, k1.y, k1.z, k1.w};
    f32x2 vf[8];
    vf[0] = bfp(v0.x); vf[1] = bfp(v0.y); vf[2] = bfp(v0.z); vf[3] = bfp(v0.w);
    vf[4] = bfp(v1.x); vf[5] = bfp(v1.y); vf[6] = bfp(v1.z); vf[7] = bfp(v1.w);

    #pragma unroll
    for (int q = 0; q < 3; ++q){
      float d = qse[w][q][s][h];
      #pragma unroll
      for (int i = 0; i < 8; ++i) d = dot2bf(qp[q][i], kp[i], d);
      const float p = valid ? __expf(d) : 0.f;
      ll[q] += p;
      const f32x2 pp = {p, p};
      #pragma unroll
      for (int i = 0; i < 8; ++i) acc[q][i] += pp * vf[i];
    }
  }

  // merge across the 8 key-slot groups (lanes xor 8/16/32 share the same head)
  #pragma unroll
  for (int q = 0; q < 3; ++q){
    ll[q] += __shfl_xor(ll[q], 8);
    ll[q] += __shfl_xor(ll[q], 16);
    ll[q] += __shfl_xor(ll[q], 32);
    #pragma unroll
    for (int i = 0; i < 8; ++i){
      acc[q][i] += shfl2(acc[q][i], 8);
      acc[q][i] += shfl2(acc[q][i], 16);
      acc[q][i] += shfl2(acc[q][i], 32);
    }
  }

  // slot-group q (<3) stores query-frame q's output over its Q row (8 lanes x 32B = 256B)
  #pragma unroll
  for (int q = 0; q < 3; ++q){
    if (slot == q){
      const float inv = 1.0f / ll[q];
      uint4 o0, o1;
      {
        const f32x2 t0 = acc[q][0] * inv, t1 = acc[q][1] * inv;
        const f32x2 t2 = acc[q][2] * inv, t3 = acc[q][3] * inv;
        o0.x = (u32)f2bf(t0.x) | ((u32)f2bf(t0.y) << 16);
        o0.y = (u32)f2bf(t1.x) | ((u32)f2bf(t1.y) << 16);
        o0.z = (u32)f2bf(t2.x) | ((u32)f2bf(t2.y) << 16);
        o0.w = (u32)f2bf(t3.x) | ((u32)f2bf(t3.y) << 16);
      }
      {
        const f32x2 t0 = acc[q][4] * inv, t1 = acc[q][5] * inv;
        const f32x2 t2 = acc[q][6] * inv, t3 = acc[q][7] * inv;
        o1.x = (u32)f2bf(t0.x) | ((u32)f2bf(t0.y) << 16);
        o1.y = (u32)f2bf(t1.x) | ((u32)f2bf(t1.y) << 16);
        o1.z = (u32)f2bf(t2.x) | ((u32)f2bf(t2.y) << 16);
        o1.w = (u32)f2bf(t3.x) | ((u32)f2bf(t3.y) << 16);
      }
      u16* dst = Qb + ((size_t)((q * B_ + b) * Y_ + y) * X_ + x) * 128 + h * 16;
      *(uint4*)dst = o0;
      *(uint4*)(dst + 8) = o1;
    }
  }
}

// ---------------- kernel 3: output projection (attnout x Wout) ----------------
__global__ __launch_bounds__(256) void out_kernel(
    const u16* __restrict__ Ab, const u16* __restrict__ WT3, float* __restrict__ out){
  const int tid = threadIdx.x;
  const int w = tid >> 6, l = tid & 63;
  const int l16 = l & 15, lg = l >> 4;
  const int m0 = blockIdx.x * 128;

  f32x4 acc[2][8];
  #pragma unroll
  for (int mr = 0; mr < 2; ++mr)
    #pragma unroll
    for (int nf = 0; nf < 8; ++nf)
      acc[mr][nf] = (f32x4){0.f, 0.f, 0.f, 0.f};

  #pragma unroll
  for (int ks = 0; ks < 4; ++ks){
    short8 af[2];
    #pragma unroll
    for (int mr = 0; mr < 2; ++mr)
      af[mr] = *(const short8*)(Ab + (size_t)(m0 + w * 32 + mr * 16 + l16) * 128 + ks * 32 + lg * 8);
    #pragma unroll
    for (int nf = 0; nf < 8; ++nf){
      const short8 bf = *(const short8*)(WT3 + (nf * 16 + l16) * 128 + ks * 32 + lg * 8);
      acc[0][nf] = __builtin_amdgcn_mfma_f32_16x16x32_bf16(af[0], bf, acc[0][nf], 0, 0, 0);
      acc[1][nf] = __builtin_amdgcn_mfma_f32_16x16x32_bf16(af[1], bf, acc[1][nf], 0, 0, 0);
    }
  }

  #pragma unroll
  for (int mr = 0; mr < 2; ++mr)
    #pragma unroll
    for (int nf = 0; nf < 8; ++nf)
      #pragma unroll
      for (int i = 0; i < 4; ++i)
        out[(size_t)(m0 + w * 32 + mr * 16 + lg * 4 + i) * 128 + nf * 16 + l16] = acc[mr][nf][i];
}

extern "C" void kernel_launch(void* const* d_in, const int* in_sizes, int n_in,
                              void* d_out, int out_size, void* d_ws, size_t ws_size,
                              hipStream_t stream){
  const float* frames      = (const float*)d_in[0];
  const float* Wq          = (const float*)d_in[1];
  const float* Wk          = (const float*)d_in[2];
  const float* Wv          = (const float*)d_in[3];
  const float* Wo          = (const float*)d_in[4];
  const float* temp_emb    = (const float*)d_in[5];
  const float* spatial_emb = (const float*)d_in[6];

  u16* WT    = (u16*)d_ws;                      // [4][128][128] bf16 (n-major)
  u16* se_bf = WT + 4 * 16384;                  // [25][128] bf16
  u16* Qb    = WT + 68736;                      // [N_][128] bf16 (Q, then attnout)
  u16* Kb    = (u16*)d_out;                     // [N_][128] bf16 — reuse output buffer
  u16* Vb    = Kb + (size_t)N_ * 128;           // [N_][128] bf16 — exactly fills d_out
  float* out = (float*)d_out;

  wt_kernel<<<269, 256, 0, stream>>>(Wq, Wk, Wv, Wo, spatial_emb, WT, se_bf);
  qkv_kernel<<<dim3(N_ / 128, 3), 256, 0, stream>>>(frames, WT, Qb, Kb, Vb, temp_emb, spatial_emb);
  attn_kernel<<<NS_ / 4, 256, 0, stream>>>(Kb, Vb, Qb, se_bf);
  out_kernel<<<N_ / 128, 256, 0, stream>>>(Qb, WT + 3 * 16384, out);
}